// Round 1
// baseline (586.000 us; speedup 1.0000x reference)
//
#include <hip/hip_runtime.h>
#include <hip/hip_bf16.h>

#define DEVINL __device__ __forceinline__

typedef short s16x8 __attribute__((ext_vector_type(8)));
typedef float f32x4 __attribute__((ext_vector_type(4)));

static constexpr int TC = 1024;      // d_model
static constexpr int NH = 16;        // heads
static constexpr int DH = 64;        // head dim
static constexpr int TT = 2048;      // seq len
static constexpr int NB = 4;         // batch
static constexpr int MROWS = NB * TT;  // 8192

// fold 1/sqrt(Dh) * log2(e) into Q so softmax can use exp2 (v_exp_f32)
static constexpr float QSCALE = 0.18033688011112042f;  // 0.125 * 1.4426950408889634

DEVINL ushort f32_to_bf16u(float f) {
  uint u = __builtin_bit_cast(uint, f);
  u += 0x7fffu + ((u >> 16) & 1u);   // round-to-nearest-even
  return (ushort)(u >> 16);
}

DEVINL f32x4 mfma32(s16x8 a, s16x8 b, f32x4 c) {
  return __builtin_amdgcn_mfma_f32_16x16x32_bf16(a, b, c, 0, 0, 0);
}

DEVINL void gload_lds16(const void* g, void* l) {
  __builtin_amdgcn_global_load_lds((const __attribute__((address_space(1))) void*)g,
                                   (__attribute__((address_space(3))) void*)l, 16, 0, 0);
}

// ---------------- fp32 -> bf16 convert (vectorized) ----------------
__global__ void cvt_kernel(const float* __restrict__ src, ushort* __restrict__ dst, int n4) {
  int i = blockIdx.x * blockDim.x + threadIdx.x;
  if (i >= n4) return;
  float4 v = reinterpret_cast<const float4*>(src)[i];
  ushort4 o;
  o.x = f32_to_bf16u(v.x);
  o.y = f32_to_bf16u(v.y);
  o.z = f32_to_bf16u(v.z);
  o.w = f32_to_bf16u(v.w);
  reinterpret_cast<ushort4*>(dst)[i] = o;
}

// ---------------- GEMM: C[M,N] = A[M,K] * B[N,K]^T, K = 1024 ----------------
// 128x128 tile, BK=64, 4 waves (each 64x64), mfma 16x16x32 bf16.
// LDS staged via global_load_lds width-16 with XOR swizzle:
//   linear LDS dest, inverse-swizzled GLOBAL source, swizzled ds_read (rule 21).
// MODE 0: write fp32 C.  MODE 1: QKV epilogue -> q (scaled), k, vT (transposed).
template <int MODE>
__global__ __launch_bounds__(256, 2) void gemm_bt(
    const ushort* __restrict__ A, const ushort* __restrict__ Bw, float* __restrict__ Cout,
    ushort* __restrict__ Qo, ushort* __restrict__ Ko, ushort* __restrict__ Vo, int N) {
  __shared__ __align__(16) ushort As[128 * 64];
  __shared__ __align__(16) ushort Bs[128 * 64];
  const int lane = threadIdx.x & 63;
  const int wid = threadIdx.x >> 6;
  const int bx = blockIdx.x, by = blockIdx.y;
  const int wrow = (wid >> 1) * 64, wcol = (wid & 1) * 64;
  const int lr = lane >> 3;  // row within 8-row staging segment
  const int lc = lane & 7;   // 16B chunk within 128B row

  f32x4 acc[4][4] = {};

  for (int kt = 0; kt < TC; kt += 64) {
#pragma unroll
    for (int j = 0; j < 4; ++j) {
      const int seg = wid * 4 + j;
      const int r = seg * 8 + lr;
      const int csrc = lc ^ (r & 7);  // inverse swizzle on the global source
      const ushort* ga = A + (size_t)(by * 128 + r) * TC + kt + csrc * 8;
      gload_lds16(ga, &As[seg * 512]);
      const ushort* gb = Bw + (size_t)(bx * 128 + r) * TC + kt + csrc * 8;
      gload_lds16(gb, &Bs[seg * 512]);
    }
    __syncthreads();
#pragma unroll
    for (int kk = 0; kk < 2; ++kk) {
      s16x8 af[4], bfr[4];
#pragma unroll
      for (int m = 0; m < 4; ++m) {
        const int r = wrow + m * 16 + (lane & 15);
        const int ch = (kk * 4 + (lane >> 4)) ^ (r & 7);  // swizzled read
        af[m] = *reinterpret_cast<const s16x8*>(&As[r * 64 + ch * 8]);
      }
#pragma unroll
      for (int n = 0; n < 4; ++n) {
        const int r = wcol + n * 16 + (lane & 15);
        const int ch = (kk * 4 + (lane >> 4)) ^ (r & 7);
        bfr[n] = *reinterpret_cast<const s16x8*>(&Bs[r * 64 + ch * 8]);
      }
#pragma unroll
      for (int m = 0; m < 4; ++m)
#pragma unroll
        for (int n = 0; n < 4; ++n) acc[m][n] = mfma32(af[m], bfr[n], acc[m][n]);
    }
    __syncthreads();
  }

#pragma unroll
  for (int m = 0; m < 4; ++m) {
#pragma unroll
    for (int n = 0; n < 4; ++n) {
      const int ng = bx * 128 + wcol + n * 16 + (lane & 15);
      const int mg0 = by * 128 + wrow + m * 16 + (lane >> 4) * 4;
      if (MODE == 0) {
#pragma unroll
        for (int i = 0; i < 4; ++i) Cout[(size_t)(mg0 + i) * N + ng] = acc[m][n][i];
      } else {
        const int sec = ng >> 10;            // 0=Q 1=K 2=V
        const int w = ng & 1023;
        const int h = w >> 6, d = w & 63;
#pragma unroll
        for (int i = 0; i < 4; ++i) {
          const int mg = mg0 + i;
          const int t = mg & (TT - 1);
          const int b = mg >> 11;
          const int bh = b * NH + h;
          const float v = acc[m][n][i];
          if (sec == 0)
            Qo[((size_t)bh * TT + t) * DH + d] = f32_to_bf16u(v * QSCALE);
          else if (sec == 1)
            Ko[((size_t)bh * TT + t) * DH + d] = f32_to_bf16u(v);
          else
            Vo[((size_t)bh * DH + d) * TT + t] = f32_to_bf16u(v);  // V transposed
        }
      }
    }
  }
}

// ---------------- flash attention, swapped-QK^T (S^T = mfma(K, Q)) ----------------
// grid: (B*H, T/64); 4 waves/block, each wave owns 16 q-rows; KVBLK = 32.
// Lane layout: q-row = lane&15 for scores (lane-local softmax row),
// P re-layout via per-wave 80B-stride LDS rows into the K=32 A-fragment.
__global__ __launch_bounds__(256) void attn_kernel(const ushort* __restrict__ Q,
                                                   const ushort* __restrict__ K,
                                                   const ushort* __restrict__ V,
                                                   ushort* __restrict__ O) {
  __shared__ __align__(16) ushort plds[4][16 * 40];  // per wave: 16 rows x 80B
  const int lane = threadIdx.x & 63;
  const int wid = threadIdx.x >> 6;
  const int bh = blockIdx.x;
  const int q0 = blockIdx.y * 64 + wid * 16;
  const int qr = lane & 15, lg = lane >> 4;

  const ushort* Qh = Q + (size_t)bh * TT * DH;
  const ushort* Kh = K + (size_t)bh * TT * DH;
  const ushort* Vh = V + (size_t)bh * DH * TT;

  const s16x8 qf0 = *reinterpret_cast<const s16x8*>(&Qh[(q0 + qr) * DH + lg * 8]);
  const s16x8 qf1 = *reinterpret_cast<const s16x8*>(&Qh[(q0 + qr) * DH + 32 + lg * 8]);

  f32x4 acc[4] = {};
  float mrow = -INFINITY;
  float dpart = 0.f;
  char* prow = (char*)&plds[wid][0] + qr * 80;

  for (int k0 = 0; k0 < TT; k0 += 32) {
    const s16x8 kf0a = *reinterpret_cast<const s16x8*>(&Kh[(k0 + qr) * DH + lg * 8]);
    const s16x8 kf0b = *reinterpret_cast<const s16x8*>(&Kh[(k0 + qr) * DH + 32 + lg * 8]);
    const s16x8 kf1a = *reinterpret_cast<const s16x8*>(&Kh[(k0 + 16 + qr) * DH + lg * 8]);
    const s16x8 kf1b = *reinterpret_cast<const s16x8*>(&Kh[(k0 + 16 + qr) * DH + 32 + lg * 8]);
    const f32x4 z = {};
    f32x4 slo = mfma32(kf0a, qf0, z);
    slo = mfma32(kf0b, qf1, slo);
    f32x4 shi = mfma32(kf1a, qf0, z);
    shi = mfma32(kf1b, qf1, shi);
    // lane holds S[q=qr][keys k0 + lg*4 + i] (lo) and +16 (hi)

    float mx = fmaxf(fmaxf(fmaxf(slo[0], slo[1]), fmaxf(slo[2], slo[3])),
                     fmaxf(fmaxf(shi[0], shi[1]), fmaxf(shi[2], shi[3])));
    mx = fmaxf(mx, __shfl_xor(mx, 16));
    mx = fmaxf(mx, __shfl_xor(mx, 32));
    const float mnew = fmaxf(mrow, mx);
    const float c = __builtin_amdgcn_exp2f(mrow - mnew);
    float p[8];
#pragma unroll
    for (int i = 0; i < 4; ++i) {
      p[i] = __builtin_amdgcn_exp2f(slo[i] - mnew);
      p[4 + i] = __builtin_amdgcn_exp2f(shi[i] - mnew);
    }
    mrow = mnew;
    dpart = dpart * c + (((p[0] + p[1]) + (p[2] + p[3])) + ((p[4] + p[5]) + (p[6] + p[7])));

    float c4[4];
#pragma unroll
    for (int i = 0; i < 4; ++i) c4[i] = __shfl(c, lg * 4 + i);  // c for O-row lg*4+i
#pragma unroll
    for (int g = 0; g < 4; ++g)
#pragma unroll
      for (int i = 0; i < 4; ++i) acc[g][i] *= c4[i];

    // P (bf16) -> LDS row (80B stride: 2-way-conflict only), re-read as K=32 A-frag
    uint2 lo, hi;
    lo.x = (uint)f32_to_bf16u(p[0]) | ((uint)f32_to_bf16u(p[1]) << 16);
    lo.y = (uint)f32_to_bf16u(p[2]) | ((uint)f32_to_bf16u(p[3]) << 16);
    hi.x = (uint)f32_to_bf16u(p[4]) | ((uint)f32_to_bf16u(p[5]) << 16);
    hi.y = (uint)f32_to_bf16u(p[6]) | ((uint)f32_to_bf16u(p[7]) << 16);
    *reinterpret_cast<uint2*>(prow + lg * 8) = lo;        // keys lg*4..+3
    *reinterpret_cast<uint2*>(prow + 32 + lg * 8) = hi;   // keys 16+lg*4..+3
    const s16x8 pa = *reinterpret_cast<const s16x8*>(prow + lg * 16);  // keys lg*8..+7

#pragma unroll
    for (int g = 0; g < 4; ++g) {
      const s16x8 vf = *reinterpret_cast<const s16x8*>(&Vh[(g * 16 + qr) * TT + k0 + lg * 8]);
      acc[g] = mfma32(pa, vf, acc[g]);  // O[q=lg*4+i][d=g*16+qr]
    }
  }

  float dsum = dpart + __shfl_xor(dpart, 16);
  dsum += __shfl_xor(dsum, 32);
  float r4[4];
#pragma unroll
  for (int i = 0; i < 4; ++i) r4[i] = __shfl(dsum, lg * 4 + i);

  const int b = bh >> 4, h = bh & 15;
#pragma unroll
  for (int g = 0; g < 4; ++g) {
#pragma unroll
    for (int i = 0; i < 4; ++i) {
      const int t = q0 + lg * 4 + i;
      const int col = h * DH + g * 16 + qr;
      O[((size_t)b * TT + t) * TC + col] = f32_to_bf16u(acc[g][i] / r4[i]);
    }
  }
}

// ---------------- launch ----------------
extern "C" void kernel_launch(void* const* d_in, const int* in_sizes, int n_in,
                              void* d_out, int out_size, void* d_ws, size_t ws_size,
                              hipStream_t stream) {
  const float* x = (const float*)d_in[0];
  const float* wqkv = (const float*)d_in[1];
  const float* wout = (const float*)d_in[2];
  float* out = (float*)d_out;
  char* ws = (char*)d_ws;

  // workspace layout (72 MB total); xb is dead after GEMM1 so attn output reuses it
  ushort* xb    = (ushort*)(ws);                        // 16 MB, later attn_out
  ushort* wqkvb = (ushort*)(ws + ((size_t)16 << 20));   // 6 MB
  ushort* woutb = (ushort*)(ws + ((size_t)22 << 20));   // 2 MB
  ushort* qb    = (ushort*)(ws + ((size_t)24 << 20));   // 16 MB
  ushort* kb    = (ushort*)(ws + ((size_t)40 << 20));   // 16 MB
  ushort* vtb   = (ushort*)(ws + ((size_t)56 << 20));   // 16 MB

  {
    const int n4x = MROWS * TC / 4;
    cvt_kernel<<<(n4x + 255) / 256, 256, 0, stream>>>(x, xb, n4x);
    const int n4w = 3 * TC * TC / 4;
    cvt_kernel<<<(n4w + 255) / 256, 256, 0, stream>>>(wqkv, wqkvb, n4w);
    const int n4o = TC * TC / 4;
    cvt_kernel<<<(n4o + 255) / 256, 256, 0, stream>>>(wout, woutb, n4o);
  }

  gemm_bt<1><<<dim3(3 * TC / 128, MROWS / 128), 256, 0, stream>>>(
      xb, wqkvb, nullptr, qb, kb, vtb, 3 * TC);

  attn_kernel<<<dim3(NB * NH, TT / 64), 256, 0, stream>>>(qb, kb, vtb, xb);

  gemm_bt<0><<<dim3(TC / 128, MROWS / 128), 256, 0, stream>>>(
      xb, woutb, out, nullptr, nullptr, nullptr, TC);
}